// Round 1
// baseline (227.483 us; speedup 1.0000x reference)
//
#include <hip/hip_runtime.h>

// Problem constants: x (N,S,C,V) = (8,2048,4,64) fp32; embedding (C,K,V) = (4,512,64) fp32.
#define NROW 16384   // N*S
#define CCH  4
#define KCB  512
#define VDIM 64

// Pre-kernel: e2[c*K+k] = sum_v emb[c][k][v]^2   (C*K = 2048 values into d_ws)
__global__ void e2_kernel(const float* __restrict__ emb, float* __restrict__ e2) {
    int i = blockIdx.x * blockDim.x + threadIdx.x;
    if (i >= CCH * KCB) return;
    const float* e = emb + (size_t)i * VDIM;
    float s = 0.f;
#pragma unroll
    for (int v = 0; v < VDIM; ++v) s = fmaf(e[v], e[v], s);
    e2[i] = s;
}

// Main kernel: block = (64 rows, 4 channels, 2 K-halves) = 512 threads, 8 waves.
// Each wave: uniform (c, z) -> embedding reads are wave-uniform (scalar loads).
// Each thread: one (row, c), scans 256 codes with 4 parallel accumulator chains.
__global__ __launch_bounds__(512, 2)
void vq_kernel(const float* __restrict__ x, const float* __restrict__ emb,
               const float* __restrict__ e2w, float* __restrict__ out) {
    const int lane = threadIdx.x;                                   // row within tile
    const int c = __builtin_amdgcn_readfirstlane(threadIdx.y);      // wave-uniform channel
    const int z = __builtin_amdgcn_readfirstlane(threadIdx.z);      // wave-uniform K-half
    const int r = blockIdx.x * 64 + lane;

    // x row -> 64 VGPRs
    float xr[VDIM];
    const float4* xp = (const float4*)(x + ((size_t)r * CCH + c) * VDIM);
#pragma unroll
    for (int i = 0; i < 16; ++i) {
        const float4 t = xp[i];
        xr[4*i+0] = t.x; xr[4*i+1] = t.y; xr[4*i+2] = t.z; xr[4*i+3] = t.w;
    }
    float x2 = 0.f;
#pragma unroll
    for (int v = 0; v < VDIM; ++v) x2 = fmaf(xr[v], xr[v], x2);

    const float* eb  = emb + (size_t)c * (KCB * VDIM);  // uniform base
    const float* e2c = e2w + c * KCB;
    const int kbase = z * (KCB / 2);

    float best = 3.4e38f;
    int bk = kbase;
    for (int kk = 0; kk < (KCB / 2) / 4; ++kk) {
        const int k0 = kbase + kk * 4;
        const float* e0 = eb + (size_t)k0 * VDIM;       // uniform -> s_load
        float a0 = 0.f, a1 = 0.f, a2 = 0.f, a3 = 0.f;
#pragma unroll
        for (int v = 0; v < VDIM; ++v) {
            const float xv = xr[v];
            a0 = fmaf(e0[v        ], xv, a0);
            a1 = fmaf(e0[v +  64  ], xv, a1);
            a2 = fmaf(e0[v + 128  ], xv, a2);
            a3 = fmaf(e0[v + 192  ], xv, a3);
        }
        // exact reference expression: (x2 - 2*xe) + e2
        const float d0 = (x2 - 2.0f * a0) + e2c[k0 + 0];
        const float d1 = (x2 - 2.0f * a1) + e2c[k0 + 1];
        const float d2 = (x2 - 2.0f * a2) + e2c[k0 + 2];
        const float d3 = (x2 - 2.0f * a3) + e2c[k0 + 3];
        if (d0 < best) { best = d0; bk = k0 + 0; }      // first-min tie-break
        if (d1 < best) { best = d1; bk = k0 + 1; }
        if (d2 < best) { best = d2; bk = k0 + 2; }
        if (d3 < best) { best = d3; bk = k0 + 3; }
    }

    // combine the two K-halves (z=1 wins only on strict <  => first-occurrence semantics)
    __shared__ float sd[2][CCH][64];
    __shared__ int   sk[2][CCH][64];
    sd[z][c][lane] = best;
    sk[z][c][lane] = bk;
    __syncthreads();

    if (z == 0) {
        const float db = sd[1][c][lane];
        const int   kb = sk[1][c][lane];
        if (db < best) { best = db; bk = kb; }

        const float4* ep = (const float4*)(eb + (size_t)bk * VDIM);
        float4* o0 = (float4*)(out + ((size_t)r * CCH + c) * VDIM);
        float s = 0.f;
#pragma unroll
        for (int i = 0; i < 16; ++i) {
            const float4 e4 = ep[i];
            float4 w;
            // out0 = (output - x) + x, exactly as reference
            w.x = (e4.x - xr[4*i+0]) + xr[4*i+0];
            w.y = (e4.y - xr[4*i+1]) + xr[4*i+1];
            w.z = (e4.z - xr[4*i+2]) + xr[4*i+2];
            w.w = (e4.w - xr[4*i+3]) + xr[4*i+3];
            o0[i] = w;
            float dx;
            dx = xr[4*i+0] - e4.x; s = fmaf(dx, dx, s);
            dx = xr[4*i+1] - e4.y; s = fmaf(dx, dx, s);
            dx = xr[4*i+2] - e4.z; s = fmaf(dx, dx, s);
            dx = xr[4*i+3] - e4.w; s = fmaf(dx, dx, s);
        }
        const size_t base1 = (size_t)NROW * CCH * VDIM;
        const size_t base2 = base1 + (size_t)NROW * CCH;
        const size_t idx = (size_t)r * CCH + c;
        out[base1 + idx] = s;   // out1
        out[base2 + idx] = s;   // out2 (identical by construction in reference)
    }
}

extern "C" void kernel_launch(void* const* d_in, const int* in_sizes, int n_in,
                              void* d_out, int out_size, void* d_ws, size_t ws_size,
                              hipStream_t stream) {
    const float* x   = (const float*)d_in[0];
    const float* emb = (const float*)d_in[1];
    float* out = (float*)d_out;
    float* e2w = (float*)d_ws;   // 2048 floats = 8 KiB

    e2_kernel<<<dim3((CCH * KCB + 255) / 256), dim3(256), 0, stream>>>(emb, e2w);
    vq_kernel<<<dim3(NROW / 64), dim3(64, CCH, 2), 0, stream>>>(x, emb, e2w, out);
}

// Round 2
// 175.142 us; speedup vs baseline: 1.2988x; 1.2988x over previous
//
#include <hip/hip_runtime.h>

// x (N,S,C,V) = (8,2048,4,64) fp32; embedding (C,K,V) = (4,512,64) fp32.
#define NROW 16384   // N*S
#define CCH  4
#define KCB  512
#define VDIM 64
#define ZW   8       // K-chunks (waves) per block; each wave scans K/ZW = 64 codes

// Pre-kernel: e2[c*K+k] = sum_v emb[c][k][v]^2  (2048 floats into d_ws)
__global__ void e2_kernel(const float* __restrict__ emb, float* __restrict__ e2) {
    int i = blockIdx.x * blockDim.x + threadIdx.x;
    if (i >= CCH * KCB) return;
    const float* e = emb + (size_t)i * VDIM;
    float s = 0.f;
#pragma unroll
    for (int v = 0; v < VDIM; ++v) s = fmaf(e[v], e[v], s);
    e2[i] = s;
}

// Block = (64 rows, 8 K-chunks) = 512 threads, 8 waves; c = blockIdx.y.
// Each wave has uniform (c, z) -> embedding reads are wave-uniform scalar loads.
// xr[] is pinned in VGPRs via an opaque asm touch so the compiler can't sink
// the x loads into the K-loop (round-1 failure mode: VGPR_Count=64, re-loads).
__global__ __launch_bounds__(512, 4)
void vq_kernel(const float* __restrict__ x, const float* __restrict__ emb,
               const float* __restrict__ e2w, float* __restrict__ out) {
    const int lane = threadIdx.x;                               // row within tile
    const int c = blockIdx.y;                                   // scalar channel
    const int z = __builtin_amdgcn_readfirstlane(threadIdx.y);  // wave-uniform K-chunk
    const int r = blockIdx.x * 64 + lane;

    // x row -> 64 VGPRs, pinned
    float xr[VDIM];
    const float4* xp = (const float4*)(x + ((size_t)r * CCH + c) * VDIM);
#pragma unroll
    for (int i = 0; i < 16; ++i) {
        const float4 t = xp[i];
        xr[4*i+0] = t.x; xr[4*i+1] = t.y; xr[4*i+2] = t.z; xr[4*i+3] = t.w;
    }
#pragma unroll
    for (int v = 0; v < VDIM; ++v) asm volatile("" : "+v"(xr[v]));  // pin in VGPRs

    float x2 = 0.f;
#pragma unroll
    for (int v = 0; v < VDIM; ++v) x2 = fmaf(xr[v], xr[v], x2);

    const float* eb  = emb + (size_t)c * (KCB * VDIM);  // wave-uniform base
    const float* e2c = e2w + c * KCB;
    const int kbase = z * (KCB / ZW);

    float best = 3.4e38f;
    int bk = kbase;
    for (int kk = 0; kk < (KCB / ZW) / 4; ++kk) {       // 16 iters x 4 codes
        const int k0 = kbase + kk * 4;
        const float* e0 = eb + (size_t)k0 * VDIM;       // uniform -> s_load
        float a0 = 0.f, a1 = 0.f, a2 = 0.f, a3 = 0.f;
#pragma unroll
        for (int v = 0; v < VDIM; ++v) {
            const float xv = xr[v];
            a0 = fmaf(e0[v      ], xv, a0);
            a1 = fmaf(e0[v +  64], xv, a1);
            a2 = fmaf(e0[v + 128], xv, a2);
            a3 = fmaf(e0[v + 192], xv, a3);
        }
        // exact reference expression/order: (x2 - 2*xe) + e2
        const float d0 = (x2 - 2.0f * a0) + e2c[k0 + 0];
        const float d1 = (x2 - 2.0f * a1) + e2c[k0 + 1];
        const float d2 = (x2 - 2.0f * a2) + e2c[k0 + 2];
        const float d3 = (x2 - 2.0f * a3) + e2c[k0 + 3];
        if (d0 < best) { best = d0; bk = k0 + 0; }      // first-min tie-break
        if (d1 < best) { best = d1; bk = k0 + 1; }
        if (d2 < best) { best = d2; bk = k0 + 2; }
        if (d3 < best) { best = d3; bk = k0 + 3; }
    }

    // Combine ZW partial argmins (z ascending, strict < => global first-min)
    __shared__ float sd[ZW][64];
    __shared__ int   sk[ZW][64];
    sd[z][lane] = best;
    sk[z][lane] = bk;
    __syncthreads();

    if (z == 0) {
#pragma unroll
        for (int w = 1; w < ZW; ++w) {
            const float dw = sd[w][lane];
            const int   kw = sk[w][lane];
            if (dw < best) { best = dw; bk = kw; }
        }

        const float4* ep = (const float4*)(eb + (size_t)bk * VDIM);
        float4* o0 = (float4*)(out + ((size_t)r * CCH + c) * VDIM);
        float s = 0.f;
#pragma unroll
        for (int i = 0; i < 16; ++i) {
            const float4 e4 = ep[i];
            float4 w;
            // out0 = (output - x) + x, exactly as reference
            w.x = (e4.x - xr[4*i+0]) + xr[4*i+0];
            w.y = (e4.y - xr[4*i+1]) + xr[4*i+1];
            w.z = (e4.z - xr[4*i+2]) + xr[4*i+2];
            w.w = (e4.w - xr[4*i+3]) + xr[4*i+3];
            o0[i] = w;
            float dx;
            dx = xr[4*i+0] - e4.x; s = fmaf(dx, dx, s);
            dx = xr[4*i+1] - e4.y; s = fmaf(dx, dx, s);
            dx = xr[4*i+2] - e4.z; s = fmaf(dx, dx, s);
            dx = xr[4*i+3] - e4.w; s = fmaf(dx, dx, s);
        }
        const size_t base1 = (size_t)NROW * CCH * VDIM;
        const size_t base2 = base1 + (size_t)NROW * CCH;
        const size_t idx = (size_t)r * CCH + c;
        out[base1 + idx] = s;   // out1
        out[base2 + idx] = s;   // out2 (identical by construction)
    }
}

extern "C" void kernel_launch(void* const* d_in, const int* in_sizes, int n_in,
                              void* d_out, int out_size, void* d_ws, size_t ws_size,
                              hipStream_t stream) {
    const float* x   = (const float*)d_in[0];
    const float* emb = (const float*)d_in[1];
    float* out = (float*)d_out;
    float* e2w = (float*)d_ws;   // 8 KiB

    e2_kernel<<<dim3((CCH * KCB + 255) / 256), dim3(256), 0, stream>>>(emb, e2w);
    vq_kernel<<<dim3(NROW / 64, CCH), dim3(64, ZW), 0, stream>>>(x, emb, e2w, out);
}